// Round 2
// baseline (22227.696 us; speedup 1.0000x reference)
//
#include <hip/hip_runtime.h>
#include <stdint.h>
#include <stddef.h>

#define T_SEQ 512
#define HDIM 512
#define CTXN 10
#define OUT_T (T_SEQ - 2 * CTXN)   // 492
#define NBLK 32                    // blocks per group
#define GM 16                      // batch rows per group
#define GC 16                      // hidden cols per block

typedef __bf16 bf16x8 __attribute__((ext_vector_type(8)));
typedef float f32x4 __attribute__((ext_vector_type(4)));
typedef unsigned short u16x4 __attribute__((ext_vector_type(4)));
typedef unsigned short u16x8 __attribute__((ext_vector_type(8)));

__device__ __forceinline__ unsigned short f2bf(float f) {
  union { float f; unsigned u; } v; v.f = f;
  unsigned r = v.u + 0x7FFFu + ((v.u >> 16) & 1u);  // RNE
  return (unsigned short)(r >> 16);
}
__device__ __forceinline__ float bf2f(unsigned short b) {
  union { unsigned u; float f; } v; v.u = ((unsigned)b) << 16;
  return v.f;
}

// ------------- split fp32 weights into (hi, lo) bf16 pairs -------------
__global__ void split_w(const float* __restrict__ wih_f, const float* __restrict__ wih_b,
                        const float* __restrict__ whh_f, const float* __restrict__ whh_b,
                        unsigned short* __restrict__ wih_hi, unsigned short* __restrict__ wih_lo,
                        unsigned short* __restrict__ whh_hi, unsigned short* __restrict__ whh_lo) {
  const int which = blockIdx.y;
  const float* src = which == 0 ? wih_f : which == 1 ? wih_b : which == 2 ? whh_f : whh_b;
  const size_t off = (which & 1) ? (size_t)1536 * HDIM : 0;
  unsigned short* dhi = (which < 2 ? wih_hi : whh_hi) + off;
  unsigned short* dlo = (which < 2 ? wih_lo : whh_lo) + off;
  size_t i = ((size_t)blockIdx.x * 256 + threadIdx.x) * 4;
  float4 v = *(const float4*)(src + i);
  u16x4 h, l;
  h.x = f2bf(v.x); l.x = f2bf(v.x - bf2f(h.x));
  h.y = f2bf(v.y); l.y = f2bf(v.y - bf2f(h.y));
  h.z = f2bf(v.z); l.z = f2bf(v.z - bf2f(h.z));
  h.w = f2bf(v.w); l.w = f2bf(v.w - bf2f(h.w));
  *(u16x4*)(dhi + i) = h;
  *(u16x4*)(dlo + i) = l;
}

// ------------- fused split-precision bidirectional GRU recurrence -------------
// 8 groups = (4 batch chunks of 16) x (2 dirs); 32 blocks/group.
// Block owns GC=16 hidden cols -> 48 gate rows of Wih AND Whh, register-resident
// as hi/lo bf16 fragments. 8 waves = (matrix m in {ih,hh}) x (K-quarter q in 0..3);
// each wave: 3 gates x 4 kchunks x 3 split-terms = 36 MFMAs/step, partials
// reduced via LDS. gi is computed in-loop (no big gi buffer needed).
__global__ __launch_bounds__(512)
void gru_rec(const float* __restrict__ x,
             const unsigned short* __restrict__ wih_hi, const unsigned short* __restrict__ wih_lo,
             const unsigned short* __restrict__ whh_hi, const unsigned short* __restrict__ whh_lo,
             const float* __restrict__ bih_f, const float* __restrict__ bhh_f,
             const float* __restrict__ bih_b, const float* __restrict__ bhh_b,
             float* __restrict__ out, unsigned int* cnt, unsigned short* hbuf) {
  const int bx = blockIdx.x;
  const int g  = bx & 7;                 // group; %8 biases same-XCD placement
  const int nb = bx >> 3;                // 0..31 -> col slice
  const int d  = g & 1;
  const int b0 = (g >> 1) * GM;
  const int tid = threadIdx.x;
  const int lane = tid & 63;
  const int wave = tid >> 6;             // 0..7
  const int lr = lane & 15, lq = lane >> 4;
  const int m = wave & 1;                // 0: ih (gi), 1: hh (gh)
  const int q = wave >> 1;               // K-quarter

  __shared__ __align__(16) unsigned short Xh[GM][HDIM + 8], Xl[GM][HDIM + 8];
  __shared__ __align__(16) unsigned short Hh[GM][HDIM + 8], Hl[GM][HDIM + 8];
  __shared__ float part[2][4][3][16][17];    // [matrix][quarter][gate][col][batch]
  __shared__ float hloc[GM][GC];             // fp32 local h slice (exact)
  __shared__ float bi_s[3][GC], bh_s[3][GC];

  if (tid < 256) hloc[tid >> 4][tid & 15] = 0.f;
  if (tid < 48) {
    int g3 = tid >> 4, j = tid & 15;
    int row = g3 * HDIM + nb * GC + j;
    bi_s[g3][j] = (d ? bih_b : bih_f)[row];
    bh_s[g3][j] = (d ? bhh_b : bhh_f)[row];
  }

  // preload weight fragments (loop-invariant): 24 frags = 96 VGPRs
  const size_t wd = (size_t)d * 1536 * HDIM;
  const unsigned short* Whi = (m ? whh_hi : wih_hi) + wd;
  const unsigned short* Wlo = (m ? whh_lo : wih_lo) + wd;
  bf16x8 wh[3][4], wl[3][4];
#pragma unroll
  for (int g3 = 0; g3 < 3; g3++)
#pragma unroll
    for (int kc = 0; kc < 4; kc++) {
      size_t ofs = (size_t)(g3 * HDIM + nb * GC + lr) * HDIM + q * 128 + kc * 32 + lq * 8;
      wh[g3][kc] = *(const bf16x8*)(Whi + ofs);
      wl[g3][kc] = *(const bf16x8*)(Wlo + ofs);
    }

  unsigned int* mycnt = cnt + g * T_SEQ;
  unsigned short* hb = hbuf + (size_t)g * 2 * 2 * GM * HDIM;   // [buf][prec][16][512]

  for (int s = 0; s < T_SEQ; s++) {
    const int t = d ? (T_SEQ - 1 - s) : s;
    // ---- stage x(t), split fp32 -> hi/lo bf16 (h-independent: before the wait)
#pragma unroll
    for (int i = 0; i < 4; i++) {
      int li = tid + i * 512;
      int b = li >> 7, c = (li & 127) * 4;
      float4 v = *(const float4*)(x + (((size_t)(b0 + b) * T_SEQ + t) << 9) + c);
      u16x4 vh, vl;
      vh.x = f2bf(v.x); vl.x = f2bf(v.x - bf2f(vh.x));
      vh.y = f2bf(v.y); vl.y = f2bf(v.y - bf2f(vh.y));
      vh.z = f2bf(v.z); vl.z = f2bf(v.z - bf2f(vh.z));
      vh.w = f2bf(v.w); vl.w = f2bf(v.w - bf2f(vh.w));
      *(u16x4*)&Xh[b][c] = vh;
      *(u16x4*)&Xl[b][c] = vl;
    }
    // ---- wait for all blocks of the group to have published h(s)
    if (s > 0 && tid == 0) {
      int it = 0;
      while (__hip_atomic_load(&mycnt[s - 1], __ATOMIC_ACQUIRE,
                               __HIP_MEMORY_SCOPE_AGENT) < NBLK) {
        if (++it > (1 << 22)) break;   // turn deadlock into wrong-but-terminating
      }
    }
    __syncthreads();
    // ---- stage h(s) hi/lo into LDS
    {
      const unsigned short* rd = hb + (size_t)(s & 1) * 2 * GM * HDIM;
#pragma unroll
      for (int i = 0; i < 4; i++) {
        int li = tid + i * 512;
        int p = li >> 10, r = li & 1023;
        int b = r >> 6, c8 = (r & 63) * 8;
        u16x8 v = *(const u16x8*)(rd + (size_t)p * GM * HDIM + b * HDIM + c8);
        if (p) *(u16x8*)&Hl[b][c8] = v;
        else   *(u16x8*)&Hh[b][c8] = v;
      }
    }
    __syncthreads();
    // ---- MFMA: per wave, 3 gate tiles, K-quarter, 3 split terms each
    {
      const unsigned short (*Aph)[HDIM + 8] = m ? Hh : Xh;
      const unsigned short (*Apl)[HDIM + 8] = m ? Hl : Xl;
      f32x4 acc[3];
      acc[0] = f32x4{0.f, 0.f, 0.f, 0.f};
      acc[1] = f32x4{0.f, 0.f, 0.f, 0.f};
      acc[2] = f32x4{0.f, 0.f, 0.f, 0.f};
#pragma unroll
      for (int kc = 0; kc < 4; kc++) {
        int col = q * 128 + kc * 32 + lq * 8;
        bf16x8 Ah = *(const bf16x8*)&Aph[lr][col];
        bf16x8 Al = *(const bf16x8*)&Apl[lr][col];
#pragma unroll
        for (int g3 = 0; g3 < 3; g3++) {
          acc[g3] = __builtin_amdgcn_mfma_f32_16x16x32_bf16(Ah, wh[g3][kc], acc[g3], 0, 0, 0);
          acc[g3] = __builtin_amdgcn_mfma_f32_16x16x32_bf16(Al, wh[g3][kc], acc[g3], 0, 0, 0);
          acc[g3] = __builtin_amdgcn_mfma_f32_16x16x32_bf16(Ah, wl[g3][kc], acc[g3], 0, 0, 0);
        }
      }
      // C layout: reg r at (lr,lq) holds D[row=lq*4+r=batch][col=lr]
#pragma unroll
      for (int g3 = 0; g3 < 3; g3++)
#pragma unroll
        for (int r = 0; r < 4; r++)
          part[m][q][g3][lr][lq * 4 + r] = acc[g3][r];
    }
    __syncthreads();
    // ---- gates: 256 threads, one (batch b, col j) each
    if (tid < 256) {
      const int b = tid >> 4, j = tid & 15;
      float ir = 0.f, iz = 0.f, inn = 0.f, hr = 0.f, hz = 0.f, hnn = 0.f;
#pragma unroll
      for (int qq = 0; qq < 4; qq++) {
        ir  += part[0][qq][0][j][b];
        iz  += part[0][qq][1][j][b];
        inn += part[0][qq][2][j][b];
        hr  += part[1][qq][0][j][b];
        hz  += part[1][qq][1][j][b];
        hnn += part[1][qq][2][j][b];
      }
      float rr = 1.f / (1.f + expf(-(ir + bi_s[0][j] + hr + bh_s[0][j])));
      float zz = 1.f / (1.f + expf(-(iz + bi_s[1][j] + hz + bh_s[1][j])));
      float nn = tanhf(inn + bi_s[2][j] + rr * (hnn + bh_s[2][j]));
      float hv = (1.f - zz) * nn + zz * hloc[b][j];
      hloc[b][j] = hv;
      unsigned short h16 = f2bf(hv);
      unsigned short l16 = f2bf(hv - bf2f(h16));
      int col = nb * GC + j;
      unsigned short* wr = hb + (size_t)((s + 1) & 1) * 2 * GM * HDIM;
      wr[b * HDIM + col] = h16;
      wr[GM * HDIM + b * HDIM + col] = l16;
      if (s >= CTXN && s < T_SEQ - CTXN) {
        float xv = bf2f(Xh[b][col]) + bf2f(Xl[b][col]);   // = x to 2^-18
        out[((size_t)(b0 + b) * OUT_T + (s - CTXN)) * 1024 + d * HDIM + col] = hv + xv;
      }
    }
    __threadfence();   // agent-scope: h' visible before signaling
    __syncthreads();
    if (tid == 0)
      __hip_atomic_fetch_add(&mycnt[s], 1u, __ATOMIC_RELEASE, __HIP_MEMORY_SCOPE_AGENT);
  }
}

extern "C" void kernel_launch(void* const* d_in, const int* in_sizes, int n_in,
                              void* d_out, int out_size, void* d_ws, size_t ws_size,
                              hipStream_t stream) {
  (void)in_sizes; (void)n_in; (void)out_size; (void)ws_size;
  const float* v_in  = (const float*)d_in[0];
  const float* Wih_f = (const float*)d_in[1];
  const float* Whh_f = (const float*)d_in[2];
  const float* bih_f = (const float*)d_in[3];
  const float* bhh_f = (const float*)d_in[4];
  const float* Wih_b = (const float*)d_in[5];
  const float* Whh_b = (const float*)d_in[6];
  const float* bih_b = (const float*)d_in[7];
  const float* bhh_b = (const float*)d_in[8];
  float* out = (float*)d_out;
  char* ws = (char*)d_ws;

  // ws layout (~13 MB total):
  //   [0, 16K)        cnt  : 8 groups x 512 steps x u32
  //   [16K, +512K)    hbuf : 8 x 2 bufs x 2 prec x 16 x 512 bf16
  //   [1M,  +3M)      wih_hi [2][1536][512] bf16
  //   [4M,  +3M)      wih_lo
  //   [7M,  +3M)      whh_hi
  //   [10M, +3M)      whh_lo
  unsigned int*  cnt    = (unsigned int*)ws;
  unsigned short* hbuf  = (unsigned short*)(ws + 16384);
  unsigned short* wih_hi = (unsigned short*)(ws + (size_t)(1 << 20));
  unsigned short* wih_lo = (unsigned short*)(ws + (size_t)(4 << 20));
  unsigned short* whh_hi = (unsigned short*)(ws + (size_t)(7 << 20));
  unsigned short* whh_lo = (unsigned short*)(ws + (size_t)(10 << 20));

  hipMemsetAsync(ws, 0, 16384 + 2 * 2 * 8 * GM * HDIM * sizeof(unsigned short), stream);
  split_w<<<dim3(768, 4), 256, 0, stream>>>(Wih_f, Wih_b, Whh_f, Whh_b,
                                            wih_hi, wih_lo, whh_hi, whh_lo);
  gru_rec<<<256, 512, 0, stream>>>(v_in, wih_hi, wih_lo, whh_hi, whh_lo,
                                   bih_f, bhh_f, bih_b, bhh_b, out, cnt, hbuf);
}

// Round 3
// 2595.736 us; speedup vs baseline: 8.5632x; 8.5632x over previous
//
#include <hip/hip_runtime.h>
#include <stdint.h>
#include <stddef.h>

#define T_SEQ 512
#define HDIM 512
#define CTXN 10
#define OUT_T (T_SEQ - 2 * CTXN)   // 492
#define NBLK 32                    // blocks per group
#define GM 16                      // batch rows per group
#define GC 16                      // hidden cols per block

typedef __bf16 bf16x8 __attribute__((ext_vector_type(8)));
typedef float f32x4 __attribute__((ext_vector_type(4)));
typedef unsigned short u16x4 __attribute__((ext_vector_type(4)));
typedef unsigned short u16x8 __attribute__((ext_vector_type(8)));

__device__ __forceinline__ unsigned short f2bf(float f) {
  union { float f; unsigned u; } v; v.f = f;
  unsigned r = v.u + 0x7FFFu + ((v.u >> 16) & 1u);  // RNE
  return (unsigned short)(r >> 16);
}
__device__ __forceinline__ float bf2f(unsigned short b) {
  union { unsigned u; float f; } v; v.u = ((unsigned)b) << 16;
  return v.f;
}

// ------------- split fp32 weights into (hi, lo) bf16 pairs -------------
__global__ void split_w(const float* __restrict__ wih_f, const float* __restrict__ wih_b,
                        const float* __restrict__ whh_f, const float* __restrict__ whh_b,
                        unsigned short* __restrict__ wih_hi, unsigned short* __restrict__ wih_lo,
                        unsigned short* __restrict__ whh_hi, unsigned short* __restrict__ whh_lo) {
  const int which = blockIdx.y;
  const float* src = which == 0 ? wih_f : which == 1 ? wih_b : which == 2 ? whh_f : whh_b;
  const size_t off = (which & 1) ? (size_t)1536 * HDIM : 0;
  unsigned short* dhi = (which < 2 ? wih_hi : whh_hi) + off;
  unsigned short* dlo = (which < 2 ? wih_lo : whh_lo) + off;
  size_t i = ((size_t)blockIdx.x * 256 + threadIdx.x) * 4;
  float4 v = *(const float4*)(src + i);
  u16x4 h, l;
  h.x = f2bf(v.x); l.x = f2bf(v.x - bf2f(h.x));
  h.y = f2bf(v.y); l.y = f2bf(v.y - bf2f(h.y));
  h.z = f2bf(v.z); l.z = f2bf(v.z - bf2f(h.z));
  h.w = f2bf(v.w); l.w = f2bf(v.w - bf2f(h.w));
  *(u16x4*)(dhi + i) = h;
  *(u16x4*)(dlo + i) = l;
}

// ------------- fused split-precision bidirectional GRU recurrence -------------
// 8 groups = (4 batch chunks of 16) x (2 dirs); 32 blocks/group.
// Same structure as the passing round-2 kernel; sync protocol rebuilt with
// relaxed agent-scope (LLC-coherent, sc0/sc1) ops — NO buffer_wbl2/buffer_inv.
__global__ __launch_bounds__(512)
void gru_rec(const float* __restrict__ x,
             const unsigned short* __restrict__ wih_hi, const unsigned short* __restrict__ wih_lo,
             const unsigned short* __restrict__ whh_hi, const unsigned short* __restrict__ whh_lo,
             const float* __restrict__ bih_f, const float* __restrict__ bhh_f,
             const float* __restrict__ bih_b, const float* __restrict__ bhh_b,
             float* __restrict__ out, unsigned int* cnt, unsigned int* hbuf) {
  const int bx = blockIdx.x;
  const int g  = bx & 7;                 // group; %8 biases same-XCD placement
  const int nb = bx >> 3;                // 0..31 -> col slice
  const int d  = g & 1;
  const int b0 = (g >> 1) * GM;
  const int tid = threadIdx.x;
  const int lane = tid & 63;
  const int wave = tid >> 6;             // 0..7
  const int lr = lane & 15, lq = lane >> 4;
  const int m = wave & 1;                // 0: ih (gi), 1: hh (gh)
  const int q = wave >> 1;               // K-quarter

  __shared__ __align__(16) unsigned short Xh[GM][HDIM + 8], Xl[GM][HDIM + 8];
  __shared__ __align__(16) unsigned short Hh[GM][HDIM + 8], Hl[GM][HDIM + 8];
  __shared__ float part[2][4][3][16][17];    // [matrix][quarter][gate][col][batch]
  __shared__ float hloc[GM][GC];             // fp32 local h slice (exact)
  __shared__ float bi_s[3][GC], bh_s[3][GC];

  if (tid < 256) hloc[tid >> 4][tid & 15] = 0.f;
  if (tid < 48) {
    int g3 = tid >> 4, j = tid & 15;
    int row = g3 * HDIM + nb * GC + j;
    bi_s[g3][j] = (d ? bih_b : bih_f)[row];
    bh_s[g3][j] = (d ? bhh_b : bhh_f)[row];
  }

  // preload weight fragments (loop-invariant): 24 frags = 96 VGPRs
  const size_t wd = (size_t)d * 1536 * HDIM;
  const unsigned short* Whi = (m ? whh_hi : wih_hi) + wd;
  const unsigned short* Wlo = (m ? whh_lo : wih_lo) + wd;
  bf16x8 wh[3][4], wl[3][4];
#pragma unroll
  for (int g3 = 0; g3 < 3; g3++)
#pragma unroll
    for (int kc = 0; kc < 4; kc++) {
      size_t ofs = (size_t)(g3 * HDIM + nb * GC + lr) * HDIM + q * 128 + kc * 32 + lq * 8;
      wh[g3][kc] = *(const bf16x8*)(Whi + ofs);
      wl[g3][kc] = *(const bf16x8*)(Wlo + ofs);
    }

  unsigned int* mycnt = cnt + g * T_SEQ;
  unsigned int* hb = hbuf + (size_t)g * 2 * GM * HDIM;   // [buf][16][512] u32 (hi<<16|lo)

  for (int s = 0; s < T_SEQ; s++) {
    const int t = d ? (T_SEQ - 1 - s) : s;
    // ---- stage x(t), split fp32 -> hi/lo bf16 (h-independent: overlaps the wait)
#pragma unroll
    for (int i = 0; i < 4; i++) {
      int li = tid + i * 512;
      int b = li >> 7, c = (li & 127) * 4;
      float4 v = *(const float4*)(x + (((size_t)(b0 + b) * T_SEQ + t) << 9) + c);
      u16x4 vh, vl;
      vh.x = f2bf(v.x); vl.x = f2bf(v.x - bf2f(vh.x));
      vh.y = f2bf(v.y); vl.y = f2bf(v.y - bf2f(vh.y));
      vh.z = f2bf(v.z); vl.z = f2bf(v.z - bf2f(vh.z));
      vh.w = f2bf(v.w); vl.w = f2bf(v.w - bf2f(vh.w));
      *(u16x4*)&Xh[b][c] = vh;
      *(u16x4*)&Xl[b][c] = vl;
    }
    // ---- wait for all blocks of the group to have published h(s)
    // Relaxed agent atomic load = LLC read (sc0 sc1), no buffer_inv per poll.
    if (s > 0 && tid == 0) {
      int it = 0;
      while (__hip_atomic_load(&mycnt[s - 1], __ATOMIC_RELAXED,
                               __HIP_MEMORY_SCOPE_AGENT) < NBLK) {
        if (++it > (1 << 22)) break;   // turn deadlock into wrong-but-terminating
      }
    }
    __syncthreads();
    // ---- read h(s) from LLC (relaxed agent 8B atomic loads bypass L1/L2),
    //      unpack packed u32 (hi<<16|lo) into Hh/Hl LDS
    {
      const unsigned long long* rd =
          (const unsigned long long*)(hb + (size_t)(s & 1) * GM * HDIM);
#pragma unroll
      for (int i = 0; i < 8; i++) {
        int li = tid + i * 512;                 // 0..4095 8B-words
        int b = li >> 8, w = li & 255;          // cols 2w, 2w+1
        unsigned long long v = __hip_atomic_load(rd + (size_t)b * 256 + w,
                                                 __ATOMIC_RELAXED, __HIP_MEMORY_SCOPE_AGENT);
        unsigned p0 = (unsigned)v, p1 = (unsigned)(v >> 32);
        *(unsigned*)&Hh[b][2 * w] = (p0 >> 16) | (p1 & 0xffff0000u);
        *(unsigned*)&Hl[b][2 * w] = (p0 & 0xffffu) | (p1 << 16);
      }
    }
    __syncthreads();
    // ---- MFMA: per wave, 3 gate tiles, K-quarter, 3 split terms each
    {
      const unsigned short (*Aph)[HDIM + 8] = m ? Hh : Xh;
      const unsigned short (*Apl)[HDIM + 8] = m ? Hl : Xl;
      f32x4 acc[3];
      acc[0] = f32x4{0.f, 0.f, 0.f, 0.f};
      acc[1] = f32x4{0.f, 0.f, 0.f, 0.f};
      acc[2] = f32x4{0.f, 0.f, 0.f, 0.f};
#pragma unroll
      for (int kc = 0; kc < 4; kc++) {
        int col = q * 128 + kc * 32 + lq * 8;
        bf16x8 Ah = *(const bf16x8*)&Aph[lr][col];
        bf16x8 Al = *(const bf16x8*)&Apl[lr][col];
#pragma unroll
        for (int g3 = 0; g3 < 3; g3++) {
          acc[g3] = __builtin_amdgcn_mfma_f32_16x16x32_bf16(Ah, wh[g3][kc], acc[g3], 0, 0, 0);
          acc[g3] = __builtin_amdgcn_mfma_f32_16x16x32_bf16(Al, wh[g3][kc], acc[g3], 0, 0, 0);
          acc[g3] = __builtin_amdgcn_mfma_f32_16x16x32_bf16(Ah, wl[g3][kc], acc[g3], 0, 0, 0);
        }
      }
      // C layout: reg r at (lr,lq) holds D[row=lq*4+r=batch][col=lr]
#pragma unroll
      for (int g3 = 0; g3 < 3; g3++)
#pragma unroll
        for (int r = 0; r < 4; r++)
          part[m][q][g3][lr][lq * 4 + r] = acc[g3][r];
    }
    __syncthreads();
    // ---- gates: 256 threads, one (batch b, col j) each
    if (tid < 256) {
      const int b = tid >> 4, j = tid & 15;
      float ir = 0.f, iz = 0.f, inn = 0.f, hr = 0.f, hz = 0.f, hnn = 0.f;
#pragma unroll
      for (int qq = 0; qq < 4; qq++) {
        ir  += part[0][qq][0][j][b];
        iz  += part[0][qq][1][j][b];
        inn += part[0][qq][2][j][b];
        hr  += part[1][qq][0][j][b];
        hz  += part[1][qq][1][j][b];
        hnn += part[1][qq][2][j][b];
      }
      float rr = 1.f / (1.f + expf(-(ir + bi_s[0][j] + hr + bh_s[0][j])));
      float zz = 1.f / (1.f + expf(-(iz + bi_s[1][j] + hz + bh_s[1][j])));
      float nn = tanhf(inn + bi_s[2][j] + rr * (hnn + bh_s[2][j]));
      float hv = (1.f - zz) * nn + zz * hloc[b][j];
      hloc[b][j] = hv;
      unsigned short h16 = f2bf(hv);
      unsigned short l16 = f2bf(hv - bf2f(h16));
      int col = nb * GC + j;
      // write-through (sc0 sc1) store to LLC: no L2 writeback needed later
      unsigned int* wr = hb + (size_t)((s + 1) & 1) * GM * HDIM;
      __hip_atomic_store(&wr[b * HDIM + col], ((unsigned)h16 << 16) | l16,
                         __ATOMIC_RELAXED, __HIP_MEMORY_SCOPE_AGENT);
      if (s >= CTXN && s < T_SEQ - CTXN) {
        float xv = bf2f(Xh[b][col]) + bf2f(Xl[b][col]);   // = x to 2^-18
        out[((size_t)(b0 + b) * OUT_T + (s - CTXN)) * 1024 + d * HDIM + col] = hv + xv;
      }
    }
    // ---- release: drain each wave's own vmem (stores AND h reads), then signal.
    asm volatile("s_waitcnt vmcnt(0)" ::: "memory");
    __syncthreads();
    if (tid == 0)
      __hip_atomic_fetch_add(&mycnt[s], 1u, __ATOMIC_RELAXED, __HIP_MEMORY_SCOPE_AGENT);
  }
}

extern "C" void kernel_launch(void* const* d_in, const int* in_sizes, int n_in,
                              void* d_out, int out_size, void* d_ws, size_t ws_size,
                              hipStream_t stream) {
  (void)in_sizes; (void)n_in; (void)out_size; (void)ws_size;
  const float* v_in  = (const float*)d_in[0];
  const float* Wih_f = (const float*)d_in[1];
  const float* Whh_f = (const float*)d_in[2];
  const float* bih_f = (const float*)d_in[3];
  const float* bhh_f = (const float*)d_in[4];
  const float* Wih_b = (const float*)d_in[5];
  const float* Whh_b = (const float*)d_in[6];
  const float* bih_b = (const float*)d_in[7];
  const float* bhh_b = (const float*)d_in[8];
  float* out = (float*)d_out;
  char* ws = (char*)d_ws;

  // ws layout (~13.5 MB total):
  //   [0, 16K)        cnt  : 8 groups x 512 steps x u32
  //   [16K, +512K)    hbuf : 8 x 2 bufs x 16 x 512 u32 (hi<<16|lo packed)
  //   [1M,  +3M)      wih_hi [2][1536][512] bf16
  //   [4M,  +3M)      wih_lo
  //   [7M,  +3M)      whh_hi
  //   [10M, +3M)      whh_lo
  unsigned int*  cnt    = (unsigned int*)ws;
  unsigned int*  hbuf   = (unsigned int*)(ws + 16384);
  unsigned short* wih_hi = (unsigned short*)(ws + (size_t)(1 << 20));
  unsigned short* wih_lo = (unsigned short*)(ws + (size_t)(4 << 20));
  unsigned short* whh_hi = (unsigned short*)(ws + (size_t)(7 << 20));
  unsigned short* whh_lo = (unsigned short*)(ws + (size_t)(10 << 20));

  hipMemsetAsync(ws, 0, 16384 + (size_t)8 * 2 * GM * HDIM * 4, stream);  // cnt + hbuf(h0=0)
  split_w<<<dim3(768, 4), 256, 0, stream>>>(Wih_f, Wih_b, Whh_f, Whh_b,
                                            wih_hi, wih_lo, whh_hi, whh_lo);
  gru_rec<<<256, 512, 0, stream>>>(v_in, wih_hi, wih_lo, whh_hi, whh_lo,
                                   bih_f, bhh_f, bih_b, bhh_b, out, cnt, hbuf);
}